// Round 1
// baseline (3607.213 us; speedup 1.0000x reference)
//
#include <hip/hip_runtime.h>
#include <float.h>

#define N_ROWS 32768
#define E_DIM  512
#define N_E    8192

#define BM 64
#define BN 256
#define BK 16

// ---------------- kernel 1: wnorm[e] = sum_k W[e][k]^2 ----------------
__global__ __launch_bounds__(256) void wnorm_kernel(const float* __restrict__ W,
                                                    float* __restrict__ wnorm) {
    int wave_id = (int)((blockIdx.x * blockDim.x + threadIdx.x) >> 6);
    int lane = threadIdx.x & 63;
    if (wave_id >= N_E) return;
    const float* row = W + (size_t)wave_id * E_DIM;
    float4 v0 = *(const float4*)(row + lane * 4);
    float4 v1 = *(const float4*)(row + 256 + lane * 4);
    float s = v0.x*v0.x + v0.y*v0.y + v0.z*v0.z + v0.w*v0.w
            + v1.x*v1.x + v1.y*v1.y + v1.z*v1.z + v1.w*v1.w;
    #pragma unroll
    for (int off = 32; off; off >>= 1) s += __shfl_down(s, off);
    if (lane == 0) wnorm[wave_id] = s;
}

// ---------------- kernel 2: fused GEMM + argmin ----------------
// Block: 256 threads = (tx in [0,32), ty in [0,8)); 8x8 micro-tile per thread.
// Block handles BM=64 rows x ALL 8192 codes (min-fold stays local).
__global__ __launch_bounds__(256) void argmin_kernel(const float* __restrict__ Z,
                                                     const float* __restrict__ W,
                                                     const float* __restrict__ wnorm,
                                                     int* __restrict__ out_idx) {
    __shared__ float As[BK][BM];   // transposed z tile
    __shared__ float Bs[BK][BN];   // transposed w tile

    const int t  = threadIdx.x;
    const int tx = t & 31;
    const int ty = t >> 5;
    const int row0 = blockIdx.x * BM;

    float minv[8];
    int   mini[8];
    #pragma unroll
    for (int r = 0; r < 8; r++) { minv[r] = FLT_MAX; mini[r] = 0; }

    for (int e0 = 0; e0 < N_E; e0 += BN) {
        float acc[8][8];
        #pragma unroll
        for (int r = 0; r < 8; r++)
            #pragma unroll
            for (int c = 0; c < 8; c++) acc[r][c] = 0.0f;

        for (int k0 = 0; k0 < E_DIM; k0 += BK) {
            // stage A: BM*BK = 1024 floats = 256 float4, one per thread
            {
                int f = t; int m = f >> 2; int kq = f & 3;
                float4 v = *(const float4*)(Z + (size_t)(row0 + m) * E_DIM + k0 + kq * 4);
                As[kq*4+0][m] = v.x; As[kq*4+1][m] = v.y;
                As[kq*4+2][m] = v.z; As[kq*4+3][m] = v.w;
            }
            // stage B: BN*BK = 4096 floats = 1024 float4, four per thread
            #pragma unroll
            for (int i = 0; i < 4; i++) {
                int f = t + i * 256; int n = f >> 2; int kq = f & 3;
                float4 v = *(const float4*)(W + (size_t)(e0 + n) * E_DIM + k0 + kq * 4);
                Bs[kq*4+0][n] = v.x; Bs[kq*4+1][n] = v.y;
                Bs[kq*4+2][n] = v.z; Bs[kq*4+3][n] = v.w;
            }
            __syncthreads();
            #pragma unroll
            for (int k = 0; k < BK; k++) {
                float a[8], b[8];
                *(float4*)&a[0] = *(const float4*)&As[k][ty * 8];
                *(float4*)&a[4] = *(const float4*)&As[k][ty * 8 + 4];
                *(float4*)&b[0] = *(const float4*)&Bs[k][tx * 8];
                *(float4*)&b[4] = *(const float4*)&Bs[k][tx * 8 + 4];
                #pragma unroll
                for (int r = 0; r < 8; r++)
                    #pragma unroll
                    for (int c = 0; c < 8; c++)
                        acc[r][c] = fmaf(a[r], b[c], acc[r][c]);
            }
            __syncthreads();
        }
        // fold: score = wnorm[e] - 2*dot ; keep lowest index on ties (e ascending)
        #pragma unroll
        for (int c = 0; c < 8; c++) {
            int e = e0 + tx * 8 + c;
            float wn = wnorm[e];
            #pragma unroll
            for (int r = 0; r < 8; r++) {
                float s = wn - 2.0f * acc[r][c];
                if (s < minv[r]) { minv[r] = s; mini[r] = e; }
            }
        }
    }

    // reduce across tx (32 lanes of a half-wave share each row)
    #pragma unroll
    for (int r = 0; r < 8; r++) {
        float v = minv[r]; int i = mini[r];
        #pragma unroll
        for (int off = 16; off >= 1; off >>= 1) {
            float ov = __shfl_xor(v, off);
            int   oi = __shfl_xor(i, off);
            if (ov < v || (ov == v && oi < i)) { v = ov; i = oi; }
        }
        if (tx == 0) out_idx[row0 + ty * 8 + r] = i;
    }
}

// ---------------- kernel 3: gather z_q, write idx, per-row loss partial ----------------
__global__ __launch_bounds__(256) void gather_loss_kernel(const float* __restrict__ Z,
                                                          const float* __restrict__ W,
                                                          const int* __restrict__ idx,
                                                          float* __restrict__ out,
                                                          float* __restrict__ partials) {
    const int n = blockIdx.x;
    const int t = threadIdx.x;
    const int e = idx[n];
    const float* zrow = Z + (size_t)n * E_DIM;
    const float* wrow = W + (size_t)e * E_DIM;

    float2 zv = *(const float2*)(zrow + t * 2);
    float2 wv = *(const float2*)(wrow + t * 2);
    float d0 = wv.x - zv.x, d1 = wv.y - zv.y;
    float s = d0 * d0 + d1 * d1;

    *(float2*)(out + 1 + (size_t)n * E_DIM + t * 2) = wv;  // z_q_st == z_q numerically

    #pragma unroll
    for (int off = 32; off; off >>= 1) s += __shfl_down(s, off);
    __shared__ float red[4];
    if ((t & 63) == 0) red[t >> 6] = s;
    __syncthreads();
    if (t == 0) {
        partials[n] = red[0] + red[1] + red[2] + red[3];
        out[1 + (size_t)N_ROWS * E_DIM + n] = (float)e;  // indices chunk as fp32
    }
}

// ---------------- kernel 4: deterministic final loss reduction ----------------
__global__ __launch_bounds__(256) void loss_reduce_kernel(const float* __restrict__ partials,
                                                          float* __restrict__ out) {
    const int t = threadIdx.x;
    float s = 0.0f;
    for (int i = t; i < N_ROWS; i += 256) s += partials[i];
    #pragma unroll
    for (int off = 32; off; off >>= 1) s += __shfl_down(s, off);
    __shared__ float red[4];
    if ((t & 63) == 0) red[t >> 6] = s;
    __syncthreads();
    if (t == 0) {
        float total = red[0] + red[1] + red[2] + red[3];
        // loss = mean((sg(zq)-z)^2) + BETA*mean((zq-sg(z))^2) = 2*mean((zq-z)^2)
        out[0] = 2.0f * total / ((float)N_ROWS * (float)E_DIM);
    }
}

extern "C" void kernel_launch(void* const* d_in, const int* in_sizes, int n_in,
                              void* d_out, int out_size, void* d_ws, size_t ws_size,
                              hipStream_t stream) {
    const float* Z = (const float*)d_in[0];
    const float* W = (const float*)d_in[1];
    float* out = (float*)d_out;

    float* wnorm    = (float*)d_ws;                                   // 8192 f
    int*   idx      = (int*)((char*)d_ws + N_E * sizeof(float));      // 32768 i
    float* partials = (float*)((char*)d_ws + (N_E + N_ROWS) * 4);     // 32768 f

    wnorm_kernel<<<N_E / 4, 256, 0, stream>>>(W, wnorm);
    argmin_kernel<<<N_ROWS / BM, 256, 0, stream>>>(Z, W, wnorm, idx);
    gather_loss_kernel<<<N_ROWS, 256, 0, stream>>>(Z, W, idx, out, partials);
    loss_reduce_kernel<<<1, 256, 0, stream>>>(partials, out);
}

// Round 2
// 1610.177 us; speedup vs baseline: 2.2403x; 2.2403x over previous
//
#include <hip/hip_runtime.h>
#include <hip/hip_bf16.h>
#include <float.h>

#define M_ROWS 32768
#define E_DIM  512
#define N_E    8192

#define BM 128
#define BN 128
#define BK 32
#define NHALF 2   // split e-range across blocks for occupancy (256 CUs, need >256 blocks)

typedef __attribute__((ext_vector_type(8))) short short8;
typedef __attribute__((ext_vector_type(4))) float f32x4;

__device__ inline void gl_lds16(const void* g, void* l) {
    __builtin_amdgcn_global_load_lds(
        (const __attribute__((address_space(1))) unsigned int*)g,
        (__attribute__((address_space(3))) unsigned int*)l, 16, 0, 0);
}

// ---------------- split fp32 -> bf16 hi + bf16 lo ----------------
__global__ __launch_bounds__(256) void split_kernel(const float* __restrict__ X,
                                                    ushort* __restrict__ H,
                                                    ushort* __restrict__ L,
                                                    int n4) {
    int i = blockIdx.x * 256 + threadIdx.x;
    if (i >= n4) return;
    float4 v = ((const float4*)X)[i];
    float c[4] = {v.x, v.y, v.z, v.w};
    ushort hh[4], ll[4];
    #pragma unroll
    for (int j = 0; j < 4; j++) {
        __hip_bfloat16 hb = __float2bfloat16(c[j]);
        float hf = __bfloat162float(hb);
        __hip_bfloat16 lb = __float2bfloat16(c[j] - hf);   // v-hf exact (Sterbenz)
        hh[j] = *(ushort*)&hb;
        ll[j] = *(ushort*)&lb;
    }
    ushort4 h = {hh[0], hh[1], hh[2], hh[3]};
    ushort4 l = {ll[0], ll[1], ll[2], ll[3]};
    ((ushort4*)H)[i] = h;
    ((ushort4*)L)[i] = l;
}

// ---------------- wnorm[e] = sum_k W[e][k]^2 (fp32) ----------------
__global__ __launch_bounds__(256) void wnorm_kernel(const float* __restrict__ W,
                                                    float* __restrict__ wnorm) {
    int wave_id = (int)((blockIdx.x * blockDim.x + threadIdx.x) >> 6);
    int lane = threadIdx.x & 63;
    if (wave_id >= N_E) return;
    const float* row = W + (size_t)wave_id * E_DIM;
    float4 v0 = *(const float4*)(row + lane * 4);
    float4 v1 = *(const float4*)(row + 256 + lane * 4);
    float s = v0.x*v0.x + v0.y*v0.y + v0.z*v0.z + v0.w*v0.w
            + v1.x*v1.x + v1.y*v1.y + v1.z*v1.z + v1.w*v1.w;
    #pragma unroll
    for (int off = 32; off; off >>= 1) s += __shfl_down(s, off);
    if (lane == 0) wnorm[wave_id] = s;
}

// ---------------- MFMA split-bf16 GEMM + per-row top-2 ----------------
// dot = Zh*Wh + Zh*Wl + Zl*Wh  as one GEMM with K' = 3*512 = 1536.
// Block: 128 rows x (N_E/NHALF) codes sweep; 4 waves (2x2), each 64x64 via 4x4
// mfma_f32_16x16x32_bf16 fragments. m97 structure: global_load_lds(16B) staging,
// single LDS buffer, 2 barriers per K-step.
__global__ __launch_bounds__(256, 2) void argmin_mfma(
        const ushort* __restrict__ Zh, const ushort* __restrict__ Zl,
        const ushort* __restrict__ Wh, const ushort* __restrict__ Wl,
        const float* __restrict__ wnorm, int* __restrict__ cand) {
    __shared__ __align__(16) ushort As[BM * BK];   // [row][k] 64B rows, 8 KB
    __shared__ __align__(16) ushort Bs[BN * BK];   // 8 KB
    __shared__ float4 SmTop[BM][2];                // cross-wave_n merge, 4 KB

    const int t = threadIdx.x;
    const int lane = t & 63;
    const int wid = t >> 6;
    const int wave_m = wid >> 1, wave_n = wid & 1;
    const int l15 = lane & 15, l4 = lane >> 4;
    const int row0 = blockIdx.x * BM;
    const int half = blockIdx.y;
    const int ebase = half * (N_E / NHALF);

    // staging constants: LDS byte o = i*4096 + t*16 -> row = i*64 + (t>>2), kelem = (t&3)*8
    const int srow = t >> 2;
    const int kq = (t & 3) * 8;
    char* aLds0 = (char*)As + t * 16;
    char* aLds1 = (char*)As + 4096 + t * 16;
    char* bLds0 = (char*)Bs + t * 16;
    char* bLds1 = (char*)Bs + 4096 + t * 16;

    // persistent per-thread top2: 16 row-slots (mi*4+r), row = wave_m*64+mi*16+l4*4+r
    float v0[16], v1[16];
    int i0[16], i1[16];
    #pragma unroll
    for (int q = 0; q < 16; q++) { v0[q] = FLT_MAX; v1[q] = FLT_MAX; i0[q] = 0; i1[q] = 0; }

    for (int e0 = 0; e0 < N_E / NHALF; e0 += BN) {
        f32x4 acc[4][4];
        #pragma unroll
        for (int mi = 0; mi < 4; mi++)
            #pragma unroll
            for (int ni = 0; ni < 4; ni++)
                acc[mi][ni] = (f32x4){0.f, 0.f, 0.f, 0.f};

        for (int kk = 0; kk < 48; kk++) {           // K' = 1536 = 48 * 32
            const int seg = kk >> 4;                // 0,1,2
            const int kseg = (kk & 15) * BK;
            const ushort* Asrc = (seg < 2) ? Zh : Zl;
            const ushort* Bsrc = (seg == 0) ? Wh : ((seg == 1) ? Wl : Wh);
            __syncthreads();                        // prev compute done before overwrite
            gl_lds16(Asrc + (size_t)(row0 + srow) * E_DIM + kseg + kq, aLds0);
            gl_lds16(Asrc + (size_t)(row0 + 64 + srow) * E_DIM + kseg + kq, aLds1);
            gl_lds16(Bsrc + (size_t)(ebase + e0 + srow) * E_DIM + kseg + kq, bLds0);
            gl_lds16(Bsrc + (size_t)(ebase + e0 + 64 + srow) * E_DIM + kseg + kq, bLds1);
            __syncthreads();                        // compiler drains vmcnt before barrier

            short8 a[4], b[4];
            const ushort* ab = As + (wave_m * 64 + l15) * BK + l4 * 8;
            const ushort* bb = Bs + (wave_n * 64 + l15) * BK + l4 * 8;
            #pragma unroll
            for (int mi = 0; mi < 4; mi++) a[mi] = *(const short8*)(ab + mi * 16 * BK);
            #pragma unroll
            for (int ni = 0; ni < 4; ni++) b[ni] = *(const short8*)(bb + ni * 16 * BK);
            #pragma unroll
            for (int mi = 0; mi < 4; mi++)
                #pragma unroll
                for (int ni = 0; ni < 4; ni++)
                    acc[mi][ni] = __builtin_amdgcn_mfma_f32_16x16x32_bf16(a[mi], b[ni], acc[mi][ni], 0, 0, 0);
        }

        // fold: score = wnorm[e] - 2*dot; D layout: col=lane&15, row=(lane>>4)*4+reg
        #pragma unroll
        for (int ni = 0; ni < 4; ni++) {
            int col = ebase + e0 + wave_n * 64 + ni * 16 + l15;
            float wn = wnorm[col];
            #pragma unroll
            for (int mi = 0; mi < 4; mi++)
                #pragma unroll
                for (int r = 0; r < 4; r++) {
                    float s = fmaf(-2.0f, acc[mi][ni][r], wn);
                    int q = mi * 4 + r;
                    if (s < v0[q])      { v1[q] = v0[q]; i1[q] = i0[q]; v0[q] = s; i0[q] = col; }
                    else if (s < v1[q]) { v1[q] = s; i1[q] = col; }
                }
        }
    }

    // 16-lane (same row) top2 butterfly merge, then cross-wave_n merge via LDS
    #pragma unroll
    for (int mi = 0; mi < 4; mi++)
        #pragma unroll
        for (int r = 0; r < 4; r++) {
            int q = mi * 4 + r;
            float a0 = v0[q], a1 = v1[q];
            int b0 = i0[q], b1 = i1[q];
            #pragma unroll
            for (int mk = 1; mk <= 8; mk <<= 1) {
                float o0 = __shfl_xor(a0, mk), o1 = __shfl_xor(a1, mk);
                int   p0 = __shfl_xor(b0, mk), p1 = __shfl_xor(b1, mk);
                bool afirst = (a0 < o0) || (a0 == o0 && b0 < p0);
                float w1v = afirst ? a1 : o1; int w1i = afirst ? b1 : p1;  // winner's 2nd
                float lv  = afirst ? o0 : a0; int li  = afirst ? p0 : b0;  // loser's 1st
                bool s2 = (w1v < lv) || (w1v == lv && w1i < li);
                a0 = afirst ? a0 : o0; b0 = afirst ? b0 : p0;
                a1 = s2 ? w1v : lv;    b1 = s2 ? w1i : li;
            }
            if (l15 == 0) {
                int rl = wave_m * 64 + mi * 16 + l4 * 4 + r;
                SmTop[rl][wave_n] = make_float4(a0, __int_as_float(b0), a1, __int_as_float(b1));
            }
        }
    __syncthreads();
    if (t < BM) {
        float4 A = SmTop[t][0], B = SmTop[t][1];
        int Ai0 = __float_as_int(A.y), Ai1 = __float_as_int(A.w);
        int Bi0 = __float_as_int(B.y), Bi1 = __float_as_int(B.w);
        bool af = (A.x < B.x) || (A.x == B.x && Ai0 < Bi0);
        float w1v = af ? A.z : B.z; int w1i = af ? Ai1 : Bi1;
        float lv  = af ? B.x : A.x; int li  = af ? Bi0 : Ai0;
        bool s2 = (w1v < lv) || (w1v == lv && w1i < li);
        int top1 = af ? Ai0 : Bi0;
        int top2 = s2 ? w1i : li;
        cand[(size_t)(row0 + t) * 4 + half * 2 + 0] = top1;
        cand[(size_t)(row0 + t) * 4 + half * 2 + 1] = top2;
    }
}

// ---------------- fp32 rescore of 4 candidates + gather z_q + loss partial ----------------
__global__ __launch_bounds__(256) void rescore_gather_loss(
        const float* __restrict__ Z, const float* __restrict__ W,
        const float* __restrict__ wnorm, const int* __restrict__ cand,
        float* __restrict__ out, float* __restrict__ partials) {
    const int n = blockIdx.x;
    const int t = threadIdx.x;
    const int lane = t & 63, wv = t >> 6;
    int c[4];
    #pragma unroll
    for (int j = 0; j < 4; j++) c[j] = cand[(size_t)n * 4 + j];
    float2 zv = ((const float2*)(Z + (size_t)n * E_DIM))[t];
    float2 wvv[4];
    float dot[4];
    #pragma unroll
    for (int j = 0; j < 4; j++) {
        wvv[j] = ((const float2*)(W + (size_t)c[j] * E_DIM))[t];
        dot[j] = zv.x * wvv[j].x + zv.y * wvv[j].y;
    }
    __shared__ float red[4][4];
    #pragma unroll
    for (int j = 0; j < 4; j++) {
        float s = dot[j];
        #pragma unroll
        for (int off = 32; off; off >>= 1) s += __shfl_down(s, off);
        if (lane == 0) red[wv][j] = s;
    }
    __syncthreads();
    float best = FLT_MAX; int bj = 0, bc = 0x7fffffff;
    #pragma unroll
    for (int j = 0; j < 4; j++) {
        float d = red[0][j] + red[1][j] + red[2][j] + red[3][j];
        float s = wnorm[c[j]] - 2.0f * d;
        if (s < best || (s == best && c[j] < bc)) { best = s; bj = j; bc = c[j]; }
    }
    float2 wq = wvv[0];                 // static-index select (rule #20)
    if (bj == 1) wq = wvv[1];
    if (bj == 2) wq = wvv[2];
    if (bj == 3) wq = wvv[3];
    ((float2*)(out + 1 + (size_t)n * E_DIM))[t] = wq;   // z_q_st == z_q numerically
    float d0 = wq.x - zv.x, d1 = wq.y - zv.y;
    float sl = d0 * d0 + d1 * d1;
    #pragma unroll
    for (int off = 32; off; off >>= 1) sl += __shfl_down(sl, off);
    __shared__ float red2[4];
    if (lane == 0) red2[wv] = sl;
    __syncthreads();
    if (t == 0) {
        partials[n] = red2[0] + red2[1] + red2[2] + red2[3];
        out[1 + (size_t)M_ROWS * E_DIM + n] = (float)bc;
    }
}

// ---------------- deterministic final loss reduction ----------------
__global__ __launch_bounds__(256) void loss_reduce_kernel(const float* __restrict__ partials,
                                                          float* __restrict__ out) {
    const int t = threadIdx.x;
    float s = 0.0f;
    for (int i = t; i < M_ROWS; i += 256) s += partials[i];
    #pragma unroll
    for (int off = 32; off; off >>= 1) s += __shfl_down(s, off);
    __shared__ float red[4];
    if ((t & 63) == 0) red[t >> 6] = s;
    __syncthreads();
    if (t == 0) {
        float total = red[0] + red[1] + red[2] + red[3];
        out[0] = 2.0f * total / ((float)M_ROWS * (float)E_DIM);  // beta=1 collapses
    }
}

extern "C" void kernel_launch(void* const* d_in, const int* in_sizes, int n_in,
                              void* d_out, int out_size, void* d_ws, size_t ws_size,
                              hipStream_t stream) {
    const float* Z = (const float*)d_in[0];
    const float* W = (const float*)d_in[1];
    float* out = (float*)d_out;

    char* p = (char*)d_ws;
    ushort* Zh = (ushort*)p;      p += (size_t)M_ROWS * E_DIM * 2;
    ushort* Zl = (ushort*)p;      p += (size_t)M_ROWS * E_DIM * 2;
    ushort* Wh = (ushort*)p;      p += (size_t)N_E * E_DIM * 2;
    ushort* Wl = (ushort*)p;      p += (size_t)N_E * E_DIM * 2;
    float* wnorm = (float*)p;     p += (size_t)N_E * 4;
    int* cand = (int*)p;          p += (size_t)M_ROWS * 4 * 4;
    float* partials = (float*)p;  p += (size_t)M_ROWS * 4;

    split_kernel<<<(M_ROWS * E_DIM / 4 + 255) / 256, 256, 0, stream>>>(Z, Zh, Zl, M_ROWS * E_DIM / 4);
    split_kernel<<<(N_E * E_DIM / 4 + 255) / 256, 256, 0, stream>>>(W, Wh, Wl, N_E * E_DIM / 4);
    wnorm_kernel<<<N_E / 4, 256, 0, stream>>>(W, wnorm);
    argmin_mfma<<<dim3(M_ROWS / BM, NHALF), 256, 0, stream>>>(Zh, Zl, Wh, Wl, wnorm, cand);
    rescore_gather_loss<<<M_ROWS, 256, 0, stream>>>(Z, W, wnorm, cand, out, partials);
    loss_reduce_kernel<<<1, 256, 0, stream>>>(partials, out);
}

// Round 4
// 1111.051 us; speedup vs baseline: 3.2467x; 1.4492x over previous
//
#include <hip/hip_runtime.h>
#include <hip/hip_fp16.h>
#include <float.h>

#define M_ROWS 32768
#define E_DIM  512
#define N_E    8192

#define BM 128
#define BN 128
#define BK 32
#define NQ 4                    // quarters of the e-range
#define EQ (N_E / NQ)           // 2048 codes per quarter

typedef __attribute__((ext_vector_type(8))) _Float16 half8;
typedef __attribute__((ext_vector_type(4))) float f32x4;

__device__ inline void gl_lds16(const void* g, void* l) {
    __builtin_amdgcn_global_load_lds(
        (const __attribute__((address_space(1))) unsigned int*)g,
        (__attribute__((address_space(3))) unsigned int*)l, 16, 0, 0);
}

// ---------------- fp32 -> fp16 (RTNE) ----------------
__global__ __launch_bounds__(256) void f16_cast_kernel(const float* __restrict__ X,
                                                       ushort* __restrict__ H,
                                                       int n4) {
    int i = blockIdx.x * 256 + threadIdx.x;
    if (i >= n4) return;
    float4 v = ((const float4*)X)[i];
    float c[4] = {v.x, v.y, v.z, v.w};
    ushort hh[4];
    #pragma unroll
    for (int j = 0; j < 4; j++) {
        __half hb = __float2half(c[j]);
        hh[j] = *(ushort*)&hb;
    }
    ushort4 h = {hh[0], hh[1], hh[2], hh[3]};
    ((ushort4*)H)[i] = h;
}

// ---------------- wnorm[e] = sum_k W[e][k]^2 (fp32, exact) ----------------
__global__ __launch_bounds__(256) void wnorm_kernel(const float* __restrict__ W,
                                                    float* __restrict__ wnorm) {
    int wave_id = (int)((blockIdx.x * blockDim.x + threadIdx.x) >> 6);
    int lane = threadIdx.x & 63;
    if (wave_id >= N_E) return;
    const float* row = W + (size_t)wave_id * E_DIM;
    float4 v0 = *(const float4*)(row + lane * 4);
    float4 v1 = *(const float4*)(row + 256 + lane * 4);
    float s = v0.x*v0.x + v0.y*v0.y + v0.z*v0.z + v0.w*v0.w
            + v1.x*v1.x + v1.y*v1.y + v1.z*v1.z + v1.w*v1.w;
    #pragma unroll
    for (int off = 32; off; off >>= 1) s += __shfl_down(s, off);
    if (lane == 0) wnorm[wave_id] = s;
}

// ---------------- fp16 MFMA screen (K=512) + per-row top-2 per QUARTER ----------------
// Approx score = wnorm[e] - 2*(z16 . w16); fp16 noise sigma ~0.01 (8x tighter
// than the failed bf16 screen), and top-2 within a 2048-code quarter fails only
// if TWO quarter-mates out-noise the true argmin. Exact fp32 rescore of the
// 8 candidates decides. XCD-chunked swizzle: 2 XCDs own each quarter, so a
// quarter's 2MB W panel is L2-resident and 128 co-resident blocks stream it
// in lockstep.
__global__ __launch_bounds__(256, 2) void argmin_mfma(
        const ushort* __restrict__ Zh, const ushort* __restrict__ Wh,
        const float* __restrict__ wnorm, int* __restrict__ cand) {
    __shared__ __align__(16) ushort As[BM * BK];   // 8 KB, [row][k], 64B rows
    __shared__ __align__(16) ushort Bs[BN * BK];   // 8 KB
    __shared__ float4 SmTop[BM][2];                // 4 KB

    const int t = threadIdx.x;
    const int lane = t & 63;
    const int wid = t >> 6;
    const int wave_m = wid >> 1, wave_n = wid & 1;
    const int l15 = lane & 15, l4 = lane >> 4;

    // chunked XCD remap (1024 blocks, 8 XCDs, 128-block chunks; bijective)
    const int id = blockIdx.x;
    const int orig = (id & 7) * 128 + (id >> 3);
    const int quarter = orig >> 8;        // 2 XCDs per quarter
    const int rowblk = orig & 255;
    const int row0 = rowblk * BM;
    const int ebase = quarter * EQ;

    const int srow = t >> 2;              // staging: row = t/4, kq = (t%4)*8 elems
    const int kq = (t & 3) * 8;
    char* aLds0 = (char*)As + t * 16;
    char* aLds1 = (char*)As + 4096 + t * 16;
    char* bLds0 = (char*)Bs + t * 16;
    char* bLds1 = (char*)Bs + 4096 + t * 16;

    // persistent per-thread top2 over 16 row-slots; row = wave_m*64+mi*16+l4*4+r
    float v0[16], v1[16];
    int i0[16], i1[16];
    #pragma unroll
    for (int q = 0; q < 16; q++) { v0[q] = FLT_MAX; v1[q] = FLT_MAX; i0[q] = 0; i1[q] = 0; }

    for (int e0 = 0; e0 < EQ; e0 += BN) {
        f32x4 acc[4][4];
        #pragma unroll
        for (int mi = 0; mi < 4; mi++)
            #pragma unroll
            for (int ni = 0; ni < 4; ni++)
                acc[mi][ni] = (f32x4){0.f, 0.f, 0.f, 0.f};

        for (int kk = 0; kk < 16; kk++) {           // K = 512 = 16 * 32
            const int kseg = kk * BK;
            __syncthreads();                        // prev compute done before overwrite
            gl_lds16(Zh + (size_t)(row0 + srow) * E_DIM + kseg + kq, aLds0);
            gl_lds16(Zh + (size_t)(row0 + 64 + srow) * E_DIM + kseg + kq, aLds1);
            gl_lds16(Wh + (size_t)(ebase + e0 + srow) * E_DIM + kseg + kq, bLds0);
            gl_lds16(Wh + (size_t)(ebase + e0 + 64 + srow) * E_DIM + kseg + kq, bLds1);
            __syncthreads();                        // drains vmcnt before barrier

            half8 a[4], b[4];
            const ushort* ab = As + (wave_m * 64 + l15) * BK + l4 * 8;
            const ushort* bb = Bs + (wave_n * 64 + l15) * BK + l4 * 8;
            #pragma unroll
            for (int mi = 0; mi < 4; mi++) a[mi] = *(const half8*)(ab + mi * 16 * BK);
            #pragma unroll
            for (int ni = 0; ni < 4; ni++) b[ni] = *(const half8*)(bb + ni * 16 * BK);
            #pragma unroll
            for (int mi = 0; mi < 4; mi++)
                #pragma unroll
                for (int ni = 0; ni < 4; ni++)
                    acc[mi][ni] = __builtin_amdgcn_mfma_f32_16x16x32_f16(a[mi], b[ni], acc[mi][ni], 0, 0, 0);
        }

        // fold: score = wnorm[e] - 2*dot; D layout: col=lane&15, row=(lane>>4)*4+reg
        #pragma unroll
        for (int ni = 0; ni < 4; ni++) {
            int col = ebase + e0 + wave_n * 64 + ni * 16 + l15;
            float wn = wnorm[col];
            #pragma unroll
            for (int mi = 0; mi < 4; mi++)
                #pragma unroll
                for (int r = 0; r < 4; r++) {
                    float s = fmaf(-2.0f, acc[mi][ni][r], wn);
                    int q = mi * 4 + r;
                    if (s < v0[q])      { v1[q] = v0[q]; i1[q] = i0[q]; v0[q] = s; i0[q] = col; }
                    else if (s < v1[q]) { v1[q] = s; i1[q] = col; }
                }
        }
    }

    // 16-lane top2 butterfly merge, then cross-wave_n merge via LDS
    #pragma unroll
    for (int mi = 0; mi < 4; mi++)
        #pragma unroll
        for (int r = 0; r < 4; r++) {
            int q = mi * 4 + r;
            float a0 = v0[q], a1 = v1[q];
            int b0 = i0[q], b1 = i1[q];
            #pragma unroll
            for (int mk = 1; mk <= 8; mk <<= 1) {
                float o0 = __shfl_xor(a0, mk), o1 = __shfl_xor(a1, mk);
                int   p0 = __shfl_xor(b0, mk), p1 = __shfl_xor(b1, mk);
                bool afirst = (a0 < o0) || (a0 == o0 && b0 < p0);
                float w1v = afirst ? a1 : o1; int w1i = afirst ? b1 : p1;
                float lv  = afirst ? o0 : a0; int li  = afirst ? p0 : b0;
                bool s2 = (w1v < lv) || (w1v == lv && w1i < li);
                a0 = afirst ? a0 : o0; b0 = afirst ? b0 : p0;
                a1 = s2 ? w1v : lv;    b1 = s2 ? w1i : li;
            }
            if (l15 == 0) {
                int rl = wave_m * 64 + mi * 16 + l4 * 4 + r;
                SmTop[rl][wave_n] = make_float4(a0, __int_as_float(b0), a1, __int_as_float(b1));
            }
        }
    __syncthreads();
    if (t < BM) {
        float4 A = SmTop[t][0], B = SmTop[t][1];
        int Ai0 = __float_as_int(A.y), Ai1 = __float_as_int(A.w);
        int Bi0 = __float_as_int(B.y), Bi1 = __float_as_int(B.w);
        bool af = (A.x < B.x) || (A.x == B.x && Ai0 < Bi0);
        float w1v = af ? A.z : B.z; int w1i = af ? Ai1 : Bi1;
        float lv  = af ? B.x : A.x; int li  = af ? Bi0 : Ai0;
        bool s2 = (w1v < lv) || (w1v == lv && w1i < li);
        int top1 = af ? Ai0 : Bi0;
        int top2 = s2 ? w1i : li;
        cand[(size_t)(row0 + t) * (2 * NQ) + quarter * 2 + 0] = top1;
        cand[(size_t)(row0 + t) * (2 * NQ) + quarter * 2 + 1] = top2;
    }
}

// ---------------- fp32 rescore of 8 candidates + gather z_q + loss partial ----------------
__global__ __launch_bounds__(256) void rescore_gather_loss(
        const float* __restrict__ Z, const float* __restrict__ W,
        const float* __restrict__ wnorm, const int* __restrict__ cand,
        float* __restrict__ out, float* __restrict__ partials) {
    const int n = blockIdx.x;
    const int t = threadIdx.x;
    const int lane = t & 63, wv = t >> 6;
    int c[8];
    #pragma unroll
    for (int j = 0; j < 8; j++) c[j] = cand[(size_t)n * 8 + j];
    float2 zv = ((const float2*)(Z + (size_t)n * E_DIM))[t];
    float2 wvv[8];
    #pragma unroll
    for (int j = 0; j < 8; j++)
        wvv[j] = ((const float2*)(W + (size_t)c[j] * E_DIM))[t];
    __shared__ float red[4][8];
    #pragma unroll
    for (int j = 0; j < 8; j++) {
        float s = zv.x * wvv[j].x + zv.y * wvv[j].y;
        #pragma unroll
        for (int off = 32; off; off >>= 1) s += __shfl_down(s, off);
        if (lane == 0) red[wv][j] = s;
    }
    __syncthreads();
    float best = FLT_MAX; int bj = 0, bc = 0x7fffffff;
    #pragma unroll
    for (int j = 0; j < 8; j++) {
        float d = red[0][j] + red[1][j] + red[2][j] + red[3][j];
        float s = wnorm[c[j]] - 2.0f * d;
        if (s < best || (s == best && c[j] < bc)) { best = s; bj = j; bc = c[j]; }
    }
    float2 wq = wvv[0];                 // static-index select (rule #20)
    #pragma unroll
    for (int j = 1; j < 8; j++) if (bj == j) wq = wvv[j];
    ((float2*)(out + 1 + (size_t)n * E_DIM))[t] = wq;   // z_q_st == z_q numerically
    float d0 = wq.x - zv.x, d1 = wq.y - zv.y;
    float sl = d0 * d0 + d1 * d1;
    #pragma unroll
    for (int off = 32; off; off >>= 1) sl += __shfl_down(sl, off);
    __shared__ float red2[4];
    if (lane == 0) red2[wv] = sl;
    __syncthreads();
    if (t == 0) {
        partials[n] = red2[0] + red2[1] + red2[2] + red2[3];
        out[1 + (size_t)M_ROWS * E_DIM + n] = (float)bc;
    }
}

// ---------------- deterministic final loss reduction ----------------
__global__ __launch_bounds__(256) void loss_reduce_kernel(const float* __restrict__ partials,
                                                          float* __restrict__ out) {
    const int t = threadIdx.x;
    float s = 0.0f;
    for (int i = t; i < M_ROWS; i += 256) s += partials[i];
    #pragma unroll
    for (int off = 32; off; off >>= 1) s += __shfl_down(s, off);
    __shared__ float red[4];
    if ((t & 63) == 0) red[t >> 6] = s;
    __syncthreads();
    if (t == 0) {
        float total = red[0] + red[1] + red[2] + red[3];
        out[0] = 2.0f * total / ((float)M_ROWS * (float)E_DIM);  // beta=1 collapses
    }
}

extern "C" void kernel_launch(void* const* d_in, const int* in_sizes, int n_in,
                              void* d_out, int out_size, void* d_ws, size_t ws_size,
                              hipStream_t stream) {
    const float* Z = (const float*)d_in[0];
    const float* W = (const float*)d_in[1];
    float* out = (float*)d_out;

    char* p = (char*)d_ws;
    ushort* Zh = (ushort*)p;      p += (size_t)M_ROWS * E_DIM * 2;
    ushort* Wh = (ushort*)p;      p += (size_t)N_E * E_DIM * 2;
    float* wnorm = (float*)p;     p += (size_t)N_E * 4;
    int* cand = (int*)p;          p += (size_t)M_ROWS * 8 * 4;
    float* partials = (float*)p;  p += (size_t)M_ROWS * 4;

    f16_cast_kernel<<<(M_ROWS * E_DIM / 4 + 255) / 256, 256, 0, stream>>>(Z, Zh, M_ROWS * E_DIM / 4);
    f16_cast_kernel<<<(N_E * E_DIM / 4 + 255) / 256, 256, 0, stream>>>(W, Wh, N_E * E_DIM / 4);
    wnorm_kernel<<<N_E / 4, 256, 0, stream>>>(W, wnorm);
    argmin_mfma<<<NQ * (M_ROWS / BM), 256, 0, stream>>>(Zh, Wh, wnorm, cand);
    rescore_gather_loss<<<M_ROWS, 256, 0, stream>>>(Z, W, wnorm, cand, out, partials);
    loss_reduce_kernel<<<1, 256, 0, stream>>>(partials, out);
}